// Round 7
// baseline (295449.341 us; speedup 1.0000x reference)
//
#include <hip/hip_runtime.h>

#define VOCAB 60
#define EMB   100
#define HID   100
#define SEQN  262144
#define NPROJ 300   // 3*HID

typedef float f32x2 __attribute__((ext_vector_type(2)));
typedef float f32x4 __attribute__((ext_vector_type(4)));

__device__ __forceinline__ float fast_sig(float x) {
    return __builtin_amdgcn_rcpf(1.0f + __builtin_amdgcn_exp2f(-1.442695041f * x));
}
__device__ __forceinline__ float fast_tanh(float x) {
    return 2.0f * __builtin_amdgcn_rcpf(1.0f + __builtin_amdgcn_exp2f(-2.885390082f * x)) - 1.0f;
}

#if __has_builtin(__builtin_elementwise_fma)
#define PKFMA(A, B, C) __builtin_elementwise_fma((A), (B), (C))
#else
__device__ __forceinline__ f32x2 pkfma_(f32x2 a, f32x2 b, f32x2 c) {
    f32x2 r; r.x = fmaf(a.x, b.x, c.x); r.y = fmaf(a.y, b.y, c.y); return r;
}
#define PKFMA pkfma_
#endif

// f32x2 slice of an f32x4 at parse-time-constant index I (0 or 2).
#define SH2(V, I) __builtin_shufflevector((V), (V), (I), (I) + 1)

// proj[v][j] = emb[v]·w_ih[j] + b_ih[j] + (j<200 ? b_hh[j] : 0)
__global__ void precompute_kernel(const float* __restrict__ emb,
                                  const float* __restrict__ w_ih,
                                  const float* __restrict__ b_ih,
                                  const float* __restrict__ b_hh,
                                  float* __restrict__ proj)
{
    int idx = blockIdx.x * blockDim.x + threadIdx.x;
    if (idx < VOCAB * NPROJ) {
        int v = idx / NPROJ, j = idx - v * NPROJ;
        float acc = b_ih[j] + (j < 2 * HID ? b_hh[j] : 0.0f);
        const float* er = emb  + v * EMB;
        const float* wr = w_ih + j * EMB;
        #pragma unroll 4
        for (int k = 0; k < EMB; ++k) acc = fmaf(er[k], wr[k], acc);
        proj[idx] = acc;
    }
}

// DS-minimal GRU: 128 threads = 2 waves (1/SIMD). Thread j (j=tid<100) owns the
// FULL gate triple for h-index j: rows j (r), 100+j (z), 200+j (n) of w_hh --
// 300 weights in registers (VGPR+AGPR unified file; waves_per_eu(1,1) -> 512
// budget). Per step: 25 broadcast ds_read_b128 of h per wave (~52 DS instr
// total vs 186 before), all gate math in-thread (u never touches LDS), ONE
// ds_write_b32 (new h_j) into a double-buffered h[2][100], ONE barrier.
__global__ __launch_bounds__(128, 1) __attribute__((amdgpu_waves_per_eu(1, 1)))
void gru_seq_kernel(const int*   __restrict__ x,
                    const float* __restrict__ b_hh,
                    const float* __restrict__ proj,
                    const float* __restrict__ w_hh,
                    float* __restrict__ out)
{
    __shared__ __align__(16) float hbuf[2][104];

    const int  tid    = threadIdx.x;
    const bool is_act = (tid < HID);
    const int  j      = is_act ? tid : (HID - 1);   // clamp for safe loads

    // Three weight rows (r, z, n) in 75 named f32x4 SSA values.
    const float* wr_r = w_hh + (      j) * HID;
    const float* wr_z = w_hh + (HID + j) * HID;
    const float* wr_n = w_hh + (2*HID + j) * HID;

    f32x4 wR0,wR1,wR2,wR3,wR4,wR5,wR6,wR7,wR8,wR9,wR10,wR11,wR12,
          wR13,wR14,wR15,wR16,wR17,wR18,wR19,wR20,wR21,wR22,wR23,wR24;
    f32x4 wZ0,wZ1,wZ2,wZ3,wZ4,wZ5,wZ6,wZ7,wZ8,wZ9,wZ10,wZ11,wZ12,
          wZ13,wZ14,wZ15,wZ16,wZ17,wZ18,wZ19,wZ20,wZ21,wZ22,wZ23,wZ24;
    f32x4 wN0,wN1,wN2,wN3,wN4,wN5,wN6,wN7,wN8,wN9,wN10,wN11,wN12,
          wN13,wN14,wN15,wN16,wN17,wN18,wN19,wN20,wN21,wN22,wN23,wN24;
#define WLOAD(J) wR##J = *(const f32x4*)(wr_r + 4*J); \
                 wZ##J = *(const f32x4*)(wr_z + 4*J); \
                 wN##J = *(const f32x4*)(wr_n + 4*J);
    WLOAD(0)  WLOAD(1)  WLOAD(2)  WLOAD(3)  WLOAD(4)
    WLOAD(5)  WLOAD(6)  WLOAD(7)  WLOAD(8)  WLOAD(9)
    WLOAD(10) WLOAD(11) WLOAD(12) WLOAD(13) WLOAD(14)
    WLOAD(15) WLOAD(16) WLOAD(17) WLOAD(18) WLOAD(19)
    WLOAD(20) WLOAD(21) WLOAD(22) WLOAD(23) WLOAD(24)
#undef WLOAD

// Chunk J (k in [4J,4J+4)): one b128 broadcast read of h + 6 packed FMAs.
#define HCHUNK(J) {                                           \
    f32x4 hv_ = hb[J];                                        \
    aR0 = PKFMA(SH2(wR##J, 0), SH2(hv_, 0), aR0);             \
    aR1 = PKFMA(SH2(wR##J, 2), SH2(hv_, 2), aR1);             \
    aZ0 = PKFMA(SH2(wZ##J, 0), SH2(hv_, 0), aZ0);             \
    aZ1 = PKFMA(SH2(wZ##J, 2), SH2(hv_, 2), aZ1);             \
    aN0 = PKFMA(SH2(wN##J, 0), SH2(hv_, 0), aN0);             \
    aN1 = PKFMA(SH2(wN##J, 2), SH2(hv_, 2), aN1); }

    const float bhn = b_hh[2 * HID + j];

    // init h = 0 in both buffers
    if (is_act) { hbuf[0][j] = 0.0f; hbuf[1][j] = 0.0f; }
    float hold = 0.0f;

    // Software-pipelined token/proj lookups (1 step of slack, L2-resident).
    int tok = x[0];
    float xr = proj[tok * NPROJ + j];
    float xz = proj[tok * NPROJ + HID + j];
    float xn = proj[tok * NPROJ + 2 * HID + j];
    int tok_next = x[1];

    __syncthreads();

    for (int t = 0; t < SEQN; ++t) {
        const int cur = t & 1;

        // Prefetch step t+1 inputs (consumed at loop tail; latency hidden).
        int   tok_nn = x[(t + 2 < SEQN) ? (t + 2) : (SEQN - 1)];
        float xr_n = proj[tok_next * NPROJ + j];
        float xz_n = proj[tok_next * NPROJ + HID + j];
        float xn_n = proj[tok_next * NPROJ + 2 * HID + j];

        // ---- dot products: 25 broadcast b128 reads + 150 pk-FMAs ----
        const f32x4* hb = (const f32x4*)hbuf[cur];
        f32x2 aR0 = {0.f, 0.f}, aR1 = {0.f, 0.f};
        f32x2 aZ0 = {0.f, 0.f}, aZ1 = {0.f, 0.f};
        f32x2 aN0 = {0.f, 0.f}, aN1 = {0.f, 0.f};
        HCHUNK(0)  HCHUNK(1)  HCHUNK(2)  HCHUNK(3)  HCHUNK(4)
        HCHUNK(5)  HCHUNK(6)  HCHUNK(7)  HCHUNK(8)  HCHUNK(9)
        HCHUNK(10) HCHUNK(11) HCHUNK(12) HCHUNK(13) HCHUNK(14)
        HCHUNK(15) HCHUNK(16) HCHUNK(17) HCHUNK(18) HCHUNK(19)
        HCHUNK(20) HCHUNK(21) HCHUNK(22) HCHUNK(23) HCHUNK(24)

        f32x2 sR = aR0 + aR1, sZ = aZ0 + aZ1, sN = aN0 + aN1;
        float ur = xr + sR.x + sR.y;
        float uz = xz + sZ.x + sZ.y;
        float un = bhn + sN.x + sN.y;

        // ---- gates (all in-thread; u never touches LDS) ----
        float r    = fast_sig(ur);
        float z    = fast_sig(uz);
        float n    = fast_tanh(xn + r * un);
        float hnew = n + z * (hold - n);

        if (is_act) hbuf[cur ^ 1][j] = hnew;   // publish h_j for next step
        hold = hnew;
        __syncthreads();                       // the ONLY barrier per step

        tok = tok_next;  tok_next = tok_nn;
        xr = xr_n;  xz = xz_n;  xn = xn_n;
    }

    if (is_act) out[j] = hold;
}

extern "C" void kernel_launch(void* const* d_in, const int* in_sizes, int n_in,
                              void* d_out, int out_size, void* d_ws, size_t ws_size,
                              hipStream_t stream)
{
    const int*   x    = (const int*)  d_in[0];
    const float* emb  = (const float*)d_in[1];
    const float* w_ih = (const float*)d_in[2];
    const float* w_hh = (const float*)d_in[3];
    const float* b_ih = (const float*)d_in[4];
    const float* b_hh = (const float*)d_in[5];
    float* out = (float*)d_out;

    float* proj = (float*)d_ws;              // 60*300 f32 = 72 KB scratch

    const int total = VOCAB * NPROJ;         // 18000
    precompute_kernel<<<(total + 255) / 256, 256, 0, stream>>>(
        emb, w_ih, b_ih, b_hh, proj);
    gru_seq_kernel<<<1, 128, 0, stream>>>(x, b_hh, proj, w_hh, out);
}

// Round 8
// 167246.790 us; speedup vs baseline: 1.7665x; 1.7665x over previous
//
#include <hip/hip_runtime.h>

#define VOCAB 60
#define EMB   100
#define HID   100
#define SEQN  262144
#define NPROJ 300   // 3*HID

typedef float f32x4 __attribute__((ext_vector_type(4)));

__device__ __forceinline__ float fast_sig(float x) {
    return __builtin_amdgcn_rcpf(1.0f + __builtin_amdgcn_exp2f(-1.442695041f * x));
}
__device__ __forceinline__ float fast_tanh(float x) {
    return 2.0f * __builtin_amdgcn_rcpf(1.0f + __builtin_amdgcn_exp2f(-2.885390082f * x)) - 1.0f;
}

// proj[v][j] = emb[v]·w_ih[j] + b_ih[j] + (j<200 ? b_hh[j] : 0)
__global__ void precompute_kernel(const float* __restrict__ emb,
                                  const float* __restrict__ w_ih,
                                  const float* __restrict__ b_ih,
                                  const float* __restrict__ b_hh,
                                  float* __restrict__ proj)
{
    int idx = blockIdx.x * blockDim.x + threadIdx.x;
    if (idx < VOCAB * NPROJ) {
        int v = idx / NPROJ, j = idx - v * NPROJ;
        float acc = b_ih[j] + (j < 2 * HID ? b_hh[j] : 0.0f);
        const float* er = emb  + v * EMB;
        const float* wr = w_ih + j * EMB;
        #pragma unroll 4
        for (int k = 0; k < EMB; ++k) acc = fmaf(er[k], wr[k], acc);
        proj[idx] = acc;
    }
}

// PIN: define D by an opaque v_mov -> NOT rematerializable; RA must keep it
// in a register (or spill visibly to scratch, which WRITE_SIZE would expose).
#define PIN(D, S) { float s_ = (S); asm("v_mov_b32 %0, %1" : "=v"(D) : "v"(s_)); }

// Declare + load + pin one 4-wide k-chunk of all three rows (12 floats).
#define DECLC(C)                                                        \
    float wr##C##_0, wr##C##_1, wr##C##_2, wr##C##_3;                   \
    float wz##C##_0, wz##C##_1, wz##C##_2, wz##C##_3;                   \
    float wn##C##_0, wn##C##_1, wn##C##_2, wn##C##_3;                   \
    if constexpr (4 * (C) < KCNT) {                                     \
        f32x4 tr = *(const f32x4*)(wp_r + 4 * (C));                     \
        f32x4 tz = *(const f32x4*)(wp_z + 4 * (C));                     \
        f32x4 tn = *(const f32x4*)(wp_n + 4 * (C));                     \
        PIN(wr##C##_0, tr.x) PIN(wr##C##_1, tr.y)                       \
        PIN(wr##C##_2, tr.z) PIN(wr##C##_3, tr.w)                       \
        PIN(wz##C##_0, tz.x) PIN(wz##C##_1, tz.y)                       \
        PIN(wz##C##_2, tz.z) PIN(wz##C##_3, tz.w)                       \
        PIN(wn##C##_0, tn.x) PIN(wn##C##_1, tn.y)                       \
        PIN(wn##C##_2, tn.z) PIN(wn##C##_3, tn.w)                       \
    } else {                                                            \
        PIN(wr##C##_0, 0.0f) PIN(wr##C##_1, 0.0f)                       \
        PIN(wr##C##_2, 0.0f) PIN(wr##C##_3, 0.0f)                       \
        PIN(wz##C##_0, 0.0f) PIN(wz##C##_1, 0.0f)                       \
        PIN(wz##C##_2, 0.0f) PIN(wz##C##_3, 0.0f)                       \
        PIN(wn##C##_0, 0.0f) PIN(wn##C##_1, 0.0f)                       \
        PIN(wn##C##_2, 0.0f) PIN(wn##C##_3, 0.0f)                       \
    }

// One k-chunk of the three dot products: 1 broadcast b128 read + 12 fmaf.
#define CHUNK(C) {                                                      \
    f32x4 hv = *(const f32x4*)(hph + 4 * (C));                          \
    aR0 = fmaf(wr##C##_0, hv.x, aR0); aZ0 = fmaf(wz##C##_0, hv.x, aZ0); \
    aN0 = fmaf(wn##C##_0, hv.x, aN0);                                   \
    aR1 = fmaf(wr##C##_1, hv.y, aR1); aZ1 = fmaf(wz##C##_1, hv.y, aZ1); \
    aN1 = fmaf(wn##C##_1, hv.y, aN1);                                   \
    aR2 = fmaf(wr##C##_2, hv.z, aR2); aZ2 = fmaf(wz##C##_2, hv.z, aZ2); \
    aN2 = fmaf(wn##C##_2, hv.z, aN2);                                   \
    aR3 = fmaf(wr##C##_3, hv.w, aR3); aZ3 = fmaf(wz##C##_3, hv.w, aZ3); \
    aN3 = fmaf(wn##C##_3, hv.w, aN3); }

// Core loop for one k-range [KLO, KLO+KCNT). Thread owns the full (r,z,n)
// row-triple for h-index j; gates computed redundantly by both groups.
template <int KLO, int KCNT>
__device__ __forceinline__ void gru_core(
    const int* __restrict__ x, const float* __restrict__ proj,
    const float* __restrict__ w_hh, const float* __restrict__ b_hh,
    float* hsh, float* pmine, const float* pother,
    int j, bool writer, float* __restrict__ out)
{
    const float* wp_r = w_hh + (          j) * HID + KLO;
    const float* wp_z = w_hh + (HID     + j) * HID + KLO;
    const float* wp_n = w_hh + (2 * HID + j) * HID + KLO;
    const float* hph  = hsh + KLO;
    const float  bhn  = b_hh[2 * HID + j];

    DECLC(0)  DECLC(1)  DECLC(2)  DECLC(3)  DECLC(4)  DECLC(5)  DECLC(6)
    DECLC(7)  DECLC(8)  DECLC(9)  DECLC(10) DECLC(11) DECLC(12)

    float hold = 0.0f;

    // Software-pipelined token/proj lookups (1 step of slack, L2-resident).
    int tok = x[0];
    float xr = proj[tok * NPROJ + j];
    float xz = proj[tok * NPROJ + HID + j];
    float xn = proj[tok * NPROJ + 2 * HID + j];
    int tok_next = x[1];

    __syncthreads();

    for (int t = 0; t < SEQN; ++t) {
        // Prefetch step t+1 inputs (consumed at loop tail; latency hidden).
        int   tok_nn = x[(t + 2 < SEQN) ? (t + 2) : (SEQN - 1)];
        float xr_n = proj[tok_next * NPROJ + j];
        float xz_n = proj[tok_next * NPROJ + HID + j];
        float xn_n = proj[tok_next * NPROJ + 2 * HID + j];

        // ---- partial dots over this group's k-range ----
        float aR0 = 0.f, aR1 = 0.f, aR2 = 0.f, aR3 = 0.f;
        float aZ0 = 0.f, aZ1 = 0.f, aZ2 = 0.f, aZ3 = 0.f;
        float aN0 = 0.f, aN1 = 0.f, aN2 = 0.f, aN3 = 0.f;
        CHUNK(0)  CHUNK(1)  CHUNK(2)  CHUNK(3)  CHUNK(4)  CHUNK(5)  CHUNK(6)
        CHUNK(7)  CHUNK(8)  CHUNK(9)  CHUNK(10) CHUNK(11) CHUNK(12)
        float sR = (aR0 + aR1) + (aR2 + aR3);
        float sZ = (aZ0 + aZ1) + (aZ2 + aZ3);
        float sN = (aN0 + aN1) + (aN2 + aN3);

        pmine[j]       = sR;
        pmine[112 + j] = sZ;
        pmine[224 + j] = sN;
        __syncthreads();                     // barrier 1: partials visible

        // ---- gates (redundant in both groups; read partner partials) ----
        float uR = sR + pother[j]       + xr;
        float uZ = sZ + pother[112 + j] + xz;
        float uN = sN + pother[224 + j] + bhn;
        float r    = fast_sig(uR);
        float z    = fast_sig(uZ);
        float n    = fast_tanh(xn + r * uN);
        float hnew = n + z * (hold - n);
        hold = hnew;
        if (writer) hsh[j] = hnew;           // group 0 publishes h_j
        __syncthreads();                     // barrier 2: h visible

        tok = tok_next;  tok_next = tok_nn;
        xr = xr_n;  xz = xz_n;  xn = xn_n;
    }

    if (writer) out[j] = hold;
}

// 256 threads = 4 waves (1/SIMD, balanced). Group 0 (waves 0,1): k in [0,48)
// (+4 zero-padded); group 1 (waves 2,3): k in [48,100). Each thread owns the
// full r/z/n row-triple for its h-index j, weights pinned via opaque v_mov
// (non-rematerializable). Two barriers/step; no global loads in the loop
// beyond the pipelined token/proj prefetch.
__global__ __launch_bounds__(256, 1) __attribute__((amdgpu_waves_per_eu(1, 1)))
void gru_seq_kernel(const int*   __restrict__ x,
                    const float* __restrict__ b_hh,
                    const float* __restrict__ proj,
                    const float* __restrict__ w_hh,
                    float* __restrict__ out)
{
    __shared__ __align__(16) float hsh[112];
    __shared__ float pbuf[2][3][112];

    const int  tid = threadIdx.x;
    const int  grp = tid >> 7;          // 0: waves 0,1   1: waves 2,3
    const int  idx = tid & 127;
    const bool act = (idx < HID);
    const int  j   = act ? idx : (HID - 1);   // clamp (dup work, benign)

    if (grp == 0 && act) hsh[j] = 0.0f;

    float*       pmine  = &pbuf[grp][0][0];
    const float* pother = &pbuf[grp ^ 1][0][0];
    const bool   writer = (grp == 0) && act;

    if (grp == 0)
        gru_core<0, 48>(x, proj, w_hh, b_hh, hsh, pmine, pother, j, writer, out);
    else
        gru_core<48, 52>(x, proj, w_hh, b_hh, hsh, pmine, pother, j, writer, out);
}

extern "C" void kernel_launch(void* const* d_in, const int* in_sizes, int n_in,
                              void* d_out, int out_size, void* d_ws, size_t ws_size,
                              hipStream_t stream)
{
    const int*   x    = (const int*)  d_in[0];
    const float* emb  = (const float*)d_in[1];
    const float* w_ih = (const float*)d_in[2];
    const float* w_hh = (const float*)d_in[3];
    const float* b_ih = (const float*)d_in[4];
    const float* b_hh = (const float*)d_in[5];
    float* out = (float*)d_out;

    float* proj = (float*)d_ws;              // 60*300 f32 = 72 KB scratch

    const int total = VOCAB * NPROJ;         // 18000
    precompute_kernel<<<(total + 255) / 256, 256, 0, stream>>>(
        emb, w_ih, b_ih, b_hh, proj);
    gru_seq_kernel<<<1, 256, 0, stream>>>(x, b_hh, proj, w_hh, out);
}

// Round 9
// 146981.909 us; speedup vs baseline: 2.0101x; 1.1379x over previous
//
#include <hip/hip_runtime.h>
#include <stdint.h>

#define VOCAB 60
#define EMB   100
#define HID   100
#define SEQN  262144
#define NPROJ 300    // 3*HID
#define WSTR  104    // f16 halves per weight row (100 + 4 zero pad, 16B-aligned)

typedef float     f32x4 __attribute__((ext_vector_type(4)));
typedef uint32_t  u32x4 __attribute__((ext_vector_type(4)));
typedef _Float16  h16x2 __attribute__((ext_vector_type(2)));
typedef _Float16  h16x8 __attribute__((ext_vector_type(8)));

__device__ __forceinline__ float fast_sig(float x) {
    return __builtin_amdgcn_rcpf(1.0f + __builtin_amdgcn_exp2f(-1.442695041f * x));
}
__device__ __forceinline__ float fast_tanh(float x) {
    return 2.0f * __builtin_amdgcn_rcpf(1.0f + __builtin_amdgcn_exp2f(-2.885390082f * x)) - 1.0f;
}

#if __has_builtin(__builtin_amdgcn_fdot2)
#define DOT2(A, B, C) __builtin_amdgcn_fdot2((A), (B), (C), false)
#else
__device__ __forceinline__ float DOT2(h16x2 a, h16x2 b, float c) {
    return fmaf((float)a.x, (float)b.x, fmaf((float)a.y, (float)b.y, c));
}
#endif

#define AS2(U)    __builtin_bit_cast(h16x2, (U))
#define SH2(V, I) __builtin_shufflevector((V), (V), (I), (I) + 1)

// PIN: define D by an opaque v_mov -> not rematerializable (round-8's proven fix).
#define PIN(D, S) asm("v_mov_b32 %0, %1" : "=v"(D) : "v"(S));

// Declare + load + pin one 8-half chunk (4 dwords) of row P from PTR.
#define PINW(P, c, PTR)                                                   \
    uint32_t P##c##_0, P##c##_1, P##c##_2, P##c##_3;                      \
    { u32x4 q_ = *(const u32x4*)((PTR) + 8 * (c));                        \
      PIN(P##c##_0, q_.x) PIN(P##c##_1, q_.y)                             \
      PIN(P##c##_2, q_.z) PIN(P##c##_3, q_.w) }

// One 8-half chunk of h (ONE broadcast b128 read) feeding all 3 rows: 12 dot2.
#define CHUNK(c) {                                                        \
    h16x8 hq_ = *(const h16x8*)(hp + 8 * (c));                            \
    h16x2 h0_ = SH2(hq_, 0), h1_ = SH2(hq_, 2);                           \
    h16x2 h2_ = SH2(hq_, 4), h3_ = SH2(hq_, 6);                           \
    aR0 = DOT2(AS2(wR##c##_0), h0_, aR0);                                 \
    aR1 = DOT2(AS2(wR##c##_1), h1_, aR1);                                 \
    aR2 = DOT2(AS2(wR##c##_2), h2_, aR2);                                 \
    aR3 = DOT2(AS2(wR##c##_3), h3_, aR3);                                 \
    aZ0 = DOT2(AS2(wZ##c##_0), h0_, aZ0);                                 \
    aZ1 = DOT2(AS2(wZ##c##_1), h1_, aZ1);                                 \
    aZ2 = DOT2(AS2(wZ##c##_2), h2_, aZ2);                                 \
    aZ3 = DOT2(AS2(wZ##c##_3), h3_, aZ3);                                 \
    aN0 = DOT2(AS2(wN##c##_0), h0_, aN0);                                 \
    aN1 = DOT2(AS2(wN##c##_1), h1_, aN1);                                 \
    aN2 = DOT2(AS2(wN##c##_2), h2_, aN2);                                 \
    aN3 = DOT2(AS2(wN##c##_3), h3_, aN3); }

// proj[v][j] = emb[v]·w_ih[j] + b_ih[j] + (j<200 ? b_hh[j] : 0)  (fp32)
// wf16[row][k] = (f16)w_hh[row][k], k<100; 0 for the 4 pad halves.
__global__ void precompute_kernel(const float* __restrict__ emb,
                                  const float* __restrict__ w_ih,
                                  const float* __restrict__ b_ih,
                                  const float* __restrict__ b_hh,
                                  const float* __restrict__ w_hh,
                                  float* __restrict__ proj,
                                  _Float16* __restrict__ wf16)
{
    int idx = blockIdx.x * blockDim.x + threadIdx.x;
    if (idx < VOCAB * NPROJ) {
        int v = idx / NPROJ, j = idx - v * NPROJ;
        float acc = b_ih[j] + (j < 2 * HID ? b_hh[j] : 0.0f);
        const float* er = emb  + v * EMB;
        const float* wr = w_ih + j * EMB;
        #pragma unroll 4
        for (int k = 0; k < EMB; ++k) acc = fmaf(er[k], wr[k], acc);
        proj[idx] = acc;
    }
    if (idx < NPROJ * WSTR) {
        int row = idx / WSTR, k = idx - row * WSTR;
        wf16[idx] = (k < HID) ? (_Float16)w_hh[row * HID + k] : (_Float16)0.0f;
    }
}

// 128 threads = 2 waves. Thread j owns the FULL (r,z,n) row-triple for h-index
// j in f16 pairs (156 pinned dwords), does 156 v_dot2_f32_f16 (fp32 accum),
// gates entirely in-thread, publishes h_j as f16 to a double-buffered LDS h.
// ONE barrier per step; recurrent state `hold` stays fp32 in-register.
__global__ __launch_bounds__(128, 1) __attribute__((amdgpu_waves_per_eu(1, 1)))
void gru_seq_kernel(const int*      __restrict__ x,
                    const float*    __restrict__ b_hh,
                    const float*    __restrict__ proj,
                    const _Float16* __restrict__ wf16,
                    float*          __restrict__ out)
{
    __shared__ __align__(16) _Float16 hbuf[2][WSTR];

    const int  tid = threadIdx.x;
    const bool act = (tid < HID);
    const int  j   = act ? tid : (HID - 1);   // clamp (dup work, benign)

    if (tid < WSTR) { hbuf[0][tid] = (_Float16)0.0f; hbuf[1][tid] = (_Float16)0.0f; }

    const _Float16* wpR = wf16 + (          j) * WSTR;
    const _Float16* wpZ = wf16 + (HID     + j) * WSTR;
    const _Float16* wpN = wf16 + (2 * HID + j) * WSTR;

    PINW(wR, 0,  wpR) PINW(wR, 1,  wpR) PINW(wR, 2,  wpR) PINW(wR, 3,  wpR)
    PINW(wR, 4,  wpR) PINW(wR, 5,  wpR) PINW(wR, 6,  wpR) PINW(wR, 7,  wpR)
    PINW(wR, 8,  wpR) PINW(wR, 9,  wpR) PINW(wR, 10, wpR) PINW(wR, 11, wpR)
    PINW(wR, 12, wpR)
    PINW(wZ, 0,  wpZ) PINW(wZ, 1,  wpZ) PINW(wZ, 2,  wpZ) PINW(wZ, 3,  wpZ)
    PINW(wZ, 4,  wpZ) PINW(wZ, 5,  wpZ) PINW(wZ, 6,  wpZ) PINW(wZ, 7,  wpZ)
    PINW(wZ, 8,  wpZ) PINW(wZ, 9,  wpZ) PINW(wZ, 10, wpZ) PINW(wZ, 11, wpZ)
    PINW(wZ, 12, wpZ)
    PINW(wN, 0,  wpN) PINW(wN, 1,  wpN) PINW(wN, 2,  wpN) PINW(wN, 3,  wpN)
    PINW(wN, 4,  wpN) PINW(wN, 5,  wpN) PINW(wN, 6,  wpN) PINW(wN, 7,  wpN)
    PINW(wN, 8,  wpN) PINW(wN, 9,  wpN) PINW(wN, 10, wpN) PINW(wN, 11, wpN)
    PINW(wN, 12, wpN)

    const float bhn = b_hh[2 * HID + j];
    float hold = 0.0f;

    // Software-pipelined token/proj lookups (1 step of slack, L2-resident).
    int tok = x[0];
    float xr = proj[tok * NPROJ + j];
    float xz = proj[tok * NPROJ + HID + j];
    float xn = proj[tok * NPROJ + 2 * HID + j];
    int tok_next = x[1];

    __syncthreads();

    for (int t = 0; t < SEQN; ++t) {
        const int cur = t & 1;

        // Prefetch step t+1 inputs (latency hidden under this step's dots).
        int   tok_nn = x[(t + 2 < SEQN) ? (t + 2) : (SEQN - 1)];
        float xr_n = proj[tok_next * NPROJ + j];
        float xz_n = proj[tok_next * NPROJ + HID + j];
        float xn_n = proj[tok_next * NPROJ + 2 * HID + j];

        // ---- full dots: 13 broadcast b128 h-reads + 156 dot2 (fp32 accum) ----
        const _Float16* hp = hbuf[cur];
        float aR0 = 0.f, aR1 = 0.f, aR2 = 0.f, aR3 = 0.f;
        float aZ0 = 0.f, aZ1 = 0.f, aZ2 = 0.f, aZ3 = 0.f;
        float aN0 = 0.f, aN1 = 0.f, aN2 = 0.f, aN3 = 0.f;
        CHUNK(0)  CHUNK(1)  CHUNK(2)  CHUNK(3)  CHUNK(4)  CHUNK(5)  CHUNK(6)
        CHUNK(7)  CHUNK(8)  CHUNK(9)  CHUNK(10) CHUNK(11) CHUNK(12)

        float uR = xr  + ((aR0 + aR1) + (aR2 + aR3));
        float uZ = xz  + ((aZ0 + aZ1) + (aZ2 + aZ3));
        float uN = bhn + ((aN0 + aN1) + (aN2 + aN3));

        // ---- gates (all in-thread) ----
        float r    = fast_sig(uR);
        float z    = fast_sig(uZ);
        float n    = fast_tanh(xn + r * uN);
        float hnew = n + z * (hold - n);
        hold = hnew;

        if (act) hbuf[cur ^ 1][j] = (_Float16)hnew;  // publish f16 copy of h_j
        __syncthreads();                             // the ONLY barrier per step

        tok = tok_next;  tok_next = tok_nn;
        xr = xr_n;  xz = xz_n;  xn = xn_n;
    }

    if (act) out[j] = hold;
}

extern "C" void kernel_launch(void* const* d_in, const int* in_sizes, int n_in,
                              void* d_out, int out_size, void* d_ws, size_t ws_size,
                              hipStream_t stream)
{
    const int*   x    = (const int*)  d_in[0];
    const float* emb  = (const float*)d_in[1];
    const float* w_ih = (const float*)d_in[2];
    const float* w_hh = (const float*)d_in[3];
    const float* b_ih = (const float*)d_in[4];
    const float* b_hh = (const float*)d_in[5];
    float* out = (float*)d_out;

    float*    proj = (float*)d_ws;                       // 18000 f32 = 72 KB
    _Float16* wf16 = (_Float16*)(proj + VOCAB * NPROJ);  // 300*104 f16 = 62.4 KB

    const int total = NPROJ * WSTR;                      // 31200 covers both jobs
    precompute_kernel<<<(total + 255) / 256, 256, 0, stream>>>(
        emb, w_ih, b_ih, b_hh, w_hh, proj, wf16);
    gru_seq_kernel<<<1, 128, 0, stream>>>(x, b_hh, proj, wf16, out);
}

// Round 10
// 129955.505 us; speedup vs baseline: 2.2735x; 1.1310x over previous
//
#include <hip/hip_runtime.h>
#include <stdint.h>

#define VOCAB 60
#define EMB   100
#define HID   100
#define SEQN  262144
#define NPROJ 300     // 3*HID
#define KPAD  128     // K padded to 4 MFMA K-steps of 32
#define MPAD  320     // rows padded to 4 waves * 5 tiles * 16
#define NMFW  4       // MFMA waves
#define MT    5       // M-tiles per MFMA wave
#define KS    4       // K-steps

typedef float    f32x4 __attribute__((ext_vector_type(4)));
typedef _Float16 h16x8 __attribute__((ext_vector_type(8)));

__device__ __forceinline__ float fast_sig(float x) {
    return __builtin_amdgcn_rcpf(1.0f + __builtin_amdgcn_exp2f(-1.442695041f * x));
}
__device__ __forceinline__ float fast_tanh(float x) {
    return 2.0f * __builtin_amdgcn_rcpf(1.0f + __builtin_amdgcn_exp2f(-2.885390082f * x)) - 1.0f;
}

// Job 1: proj[v][j] = emb[v]·w_ih[j] + b_ih[j] + (j<200 ? b_hh[j] : 0)  (fp32)
// Job 2: afrag = W_hh in MFMA A-fragment order (f16, zero-padded):
//   afrag[((((w*MT+m)*KS+ks)*64)+lane)*8+e] = Wpad[w*80+m*16+(lane&15)][ks*32+(lane>>4)*8+e]
__global__ void precompute_kernel(const float* __restrict__ emb,
                                  const float* __restrict__ w_ih,
                                  const float* __restrict__ b_ih,
                                  const float* __restrict__ b_hh,
                                  const float* __restrict__ w_hh,
                                  float* __restrict__ proj,
                                  _Float16* __restrict__ afrag)
{
    int idx = blockIdx.x * blockDim.x + threadIdx.x;
    if (idx < VOCAB * NPROJ) {
        int v = idx / NPROJ, j = idx - v * NPROJ;
        float acc = b_ih[j] + (j < 2 * HID ? b_hh[j] : 0.0f);
        const float* er = emb  + v * EMB;
        const float* wr = w_ih + j * EMB;
        #pragma unroll 4
        for (int k = 0; k < EMB; ++k) acc = fmaf(er[k], wr[k], acc);
        proj[idx] = acc;
    }
    if (idx < NMFW * MT * KS * 64 * 8) {     // 40960 halves
        int e    = idx & 7;
        int lane = (idx >> 3) & 63;
        int q    = idx >> 9;
        int ks   = q & 3;
        int q2   = q >> 2;
        int m    = q2 % MT;
        int w    = q2 / MT;
        int row  = w * 80 + m * 16 + (lane & 15);
        int k    = ks * 32 + ((lane >> 4) << 3) + e;
        afrag[idx] = (row < NPROJ && k < HID)
                   ? (_Float16)w_hh[row * HID + k] : (_Float16)0.0f;
    }
}

#define MFMA(A, B, C) __builtin_amdgcn_mfma_f32_16x16x32_f16((A), (B), (C), 0, 0, 0)

// Declare + load one A fragment (tile M, K-step K) into a named h16x8.
#define LOADF(M, K) \
    h16x8 af_##M##_##K = *(const h16x8*)(afrag + ((((wsafe*MT+(M))*KS+(K))*64) + lane) * 8);

// 384 threads = 6 waves. Waves 0-3: MFMA matvec u = W_hh·h (weights in AGPRs,
// consumed in place by MFMA). Waves 4-5: gate phase (thread j owns h_j) +
// token/proj prefetch overlapped with the MFMA phase. Two barriers per step.
__global__ __launch_bounds__(384, 2)
void gru_seq_kernel(const int*      __restrict__ x,
                    const float*    __restrict__ b_hh,
                    const float*    __restrict__ proj,
                    const _Float16* __restrict__ afrag,
                    float*          __restrict__ out)
{
    __shared__ __align__(16) _Float16 hbuf[2][KPAD];   // f16 h, double-buffered
    __shared__ __align__(16) float    u_lds[MPAD];     // matvec result

    const int  tid  = threadIdx.x;
    const int  wave = tid >> 6;
    const int  lane = tid & 63;
    const bool is_mfma = (wave < NMFW);
    const int  wsafe   = is_mfma ? wave : 0;

    const int  gidx = tid - NMFW * 64;                 // 0..127 on waves 4,5
    const bool gact = (!is_mfma) && (gidx < HID);
    const int  j    = gact ? gidx : 0;

    if (tid < 2 * KPAD) ((_Float16*)hbuf)[tid] = (_Float16)0.0f;

    // A fragments: 20 per MFMA wave (80 dwords), destined for AGPRs.
    LOADF(0,0) LOADF(0,1) LOADF(0,2) LOADF(0,3)
    LOADF(1,0) LOADF(1,1) LOADF(1,2) LOADF(1,3)
    LOADF(2,0) LOADF(2,1) LOADF(2,2) LOADF(2,3)
    LOADF(3,0) LOADF(3,1) LOADF(3,2) LOADF(3,3)
    LOADF(4,0) LOADF(4,1) LOADF(4,2) LOADF(4,3)

    const float bhn  = b_hh[2 * HID + j];
    float hold = 0.0f;

    // Gate-wave software pipeline (1 step of slack, L2-resident).
    int tok_next = 0;
    float xr = 0.f, xz = 0.f, xn = 0.f;
    float xr_n = 0.f, xz_n = 0.f, xn_n = 0.f;
    int tok_nn = 0;
    if (!is_mfma) {
        int tok = x[0];
        xr = proj[tok * NPROJ + j];
        xz = proj[tok * NPROJ + HID + j];
        xn = proj[tok * NPROJ + 2 * HID + j];
        tok_next = x[1];
    }

    __syncthreads();

    for (int t = 0; t < SEQN; ++t) {
        const int cur = t & 1;

        if (is_mfma) {
            // Pin fragments in AGPRs (loop-carried, non-rematerializable;
            // MFMA reads AGPR operands in place -> no per-use moves).
            asm("" : "+a"(af_0_0), "+a"(af_0_1), "+a"(af_0_2), "+a"(af_0_3), "+a"(af_1_0));
            asm("" : "+a"(af_1_1), "+a"(af_1_2), "+a"(af_1_3), "+a"(af_2_0), "+a"(af_2_1));
            asm("" : "+a"(af_2_2), "+a"(af_2_3), "+a"(af_3_0), "+a"(af_3_1), "+a"(af_3_2));
            asm("" : "+a"(af_3_3), "+a"(af_4_0), "+a"(af_4_1), "+a"(af_4_2), "+a"(af_4_3));

            // B-prep: all 16 B-columns = h  (4 broadcast b128 reads).
            const _Float16* hp = hbuf[cur];
            const int ko = (lane >> 4) << 3;
            h16x8 b0 = *(const h16x8*)(hp +  0 + ko);
            h16x8 b1 = *(const h16x8*)(hp + 32 + ko);
            h16x8 b2 = *(const h16x8*)(hp + 64 + ko);
            h16x8 b3 = *(const h16x8*)(hp + 96 + ko);

            f32x4 ac0 = {0.f,0.f,0.f,0.f}, ac1 = ac0, ac2 = ac0, ac3 = ac0, ac4 = ac0;
            ac0 = MFMA(af_0_0, b0, ac0); ac1 = MFMA(af_1_0, b0, ac1);
            ac2 = MFMA(af_2_0, b0, ac2); ac3 = MFMA(af_3_0, b0, ac3);
            ac4 = MFMA(af_4_0, b0, ac4);
            ac0 = MFMA(af_0_1, b1, ac0); ac1 = MFMA(af_1_1, b1, ac1);
            ac2 = MFMA(af_2_1, b1, ac2); ac3 = MFMA(af_3_1, b1, ac3);
            ac4 = MFMA(af_4_1, b1, ac4);
            ac0 = MFMA(af_0_2, b2, ac0); ac1 = MFMA(af_1_2, b2, ac1);
            ac2 = MFMA(af_2_2, b2, ac2); ac3 = MFMA(af_3_2, b2, ac3);
            ac4 = MFMA(af_4_2, b2, ac4);
            ac0 = MFMA(af_0_3, b3, ac0); ac1 = MFMA(af_1_3, b3, ac1);
            ac2 = MFMA(af_2_3, b3, ac2); ac3 = MFMA(af_3_3, b3, ac3);
            ac4 = MFMA(af_4_3, b3, ac4);

            // D: lane holds rows (lane>>4)*4+q, all cols equal; col-0 lanes write.
            if ((lane & 15) == 0) {
                const int rb = wave * 80 + ((lane >> 4) << 2);
                *(f32x4*)&u_lds[rb +  0] = ac0;
                *(f32x4*)&u_lds[rb + 16] = ac1;
                *(f32x4*)&u_lds[rb + 32] = ac2;
                *(f32x4*)&u_lds[rb + 48] = ac3;
                *(f32x4*)&u_lds[rb + 64] = ac4;
            }
        } else {
            // Overlap next step's input loads with the MFMA phase.
            tok_nn = x[(t + 2 < SEQN) ? (t + 2) : (SEQN - 1)];
            xr_n = proj[tok_next * NPROJ + j];
            xz_n = proj[tok_next * NPROJ + HID + j];
            xn_n = proj[tok_next * NPROJ + 2 * HID + j];
        }
        __syncthreads();                 // barrier 1: u visible

        if (gact) {
            float uR = u_lds[j]           + xr;
            float uZ = u_lds[HID + j]     + xz;
            float uN = u_lds[2 * HID + j] + bhn;
            float r    = fast_sig(uR);
            float z    = fast_sig(uZ);
            float n    = fast_tanh(xn + r * uN);
            float hnew = n + z * (hold - n);
            hold = hnew;
            hbuf[cur ^ 1][j] = (_Float16)hnew;
        }
        __syncthreads();                 // barrier 2: h visible

        if (!is_mfma) {
            tok_next = tok_nn;
            xr = xr_n;  xz = xz_n;  xn = xn_n;
        }
    }

    if (gact) out[j] = hold;
}

extern "C" void kernel_launch(void* const* d_in, const int* in_sizes, int n_in,
                              void* d_out, int out_size, void* d_ws, size_t ws_size,
                              hipStream_t stream)
{
    const int*   x    = (const int*)  d_in[0];
    const float* emb  = (const float*)d_in[1];
    const float* w_ih = (const float*)d_in[2];
    const float* w_hh = (const float*)d_in[3];
    const float* b_ih = (const float*)d_in[4];
    const float* b_hh = (const float*)d_in[5];
    float* out = (float*)d_out;

    float*    proj  = (float*)d_ws;                        // 18000 f32 = 72 KB
    _Float16* afrag = (_Float16*)(proj + VOCAB * NPROJ);   // 40960 f16 = 80 KB

    const int total = NMFW * MT * KS * 64 * 8;             // 40960 covers both jobs
    precompute_kernel<<<(total + 255) / 256, 256, 0, stream>>>(
        emb, w_ih, b_ih, b_hh, w_hh, proj, afrag);
    gru_seq_kernel<<<1, 384, 0, stream>>>(x, b_hh, proj, afrag, out);
}